// Round 14
// baseline (198.001 us; speedup 1.0000x reference)
//
#include <hip/hip_runtime.h>
#include <math.h>

// Problem constants
#define TT   4096
#define NBB  32
#define NUU  64
#define NHH  256
#define HH   128
#define NYY  64
// Chunking: 512 chunks of 8 steps; carry hierarchy: 16 supers x 32 chunks
#define LCH  8
#define CCH  512
#define SEGN 16
#define CPS  32

#define PI_HALF 1.5707963267948966f

typedef float  f32x16 __attribute__((ext_vector_type(16)));
typedef __bf16 bf16x8 __attribute__((ext_vector_type(8)));
typedef __bf16 bf16x2 __attribute__((ext_vector_type(2)));
typedef unsigned int uint4v __attribute__((ext_vector_type(4)));

// MFMA 32x32 C/D layout: row = (r&3) + 8*(r>>2) + 4*(lane>>5), col = lane&31
__device__ inline int crow(int r, int lane) { return (r & 3) + 8 * (r >> 2) + 4 * (lane >> 5); }
__device__ inline bf16x8 ldfrag(const unsigned short* p) {
    return __builtin_bit_cast(bf16x8, *(const uint4v*)p);
}

// split a float into bf16 hi + bf16 lo (hi+lo ~ exact to 2^-17 rel)
#define CVT(v, H, L) { __bf16 _h = (__bf16)(v); H = _h; L = (__bf16)((v) - (float)_h); }

// lambda in fp32 with correctly-rounded transcendentals (double -> fp32)
__device__ inline void lam_f32(float xre, float xim, float& lr, float& li) {
    float th = PI_HALF * xim;
    float rf = (float)exp(-(double)fabsf(xre));
    float cf = (float)cos((double)th);
    float sf = (float)sin((double)th);
    lr = rf * cf; li = rf * sf;
}

// --- swizzled LDS index helpers for pass2 (offsets in shorts) -------------
// pass2 sU (64 rows x 128): 16B chunk ^= row&15
__device__ inline int swzU(int row, int so) {
    return row * 128 + ((((so >> 3) ^ row) & 15) << 3) + (so & 7);
}
// pass2 sX (64 rows x 512): low-5 of chunk ^= row, bit5 kept
__device__ inline int swzX(int row, int so) {
    int chv = so >> 3;
    chv = (chv & 32) | ((chv ^ row) & 31);
    return row * 512 + (chv << 3) + (so & 7);
}

// ---------------------------------------------------------------------------
// Prep: x0 pairs; bf16 hi/lo split of B (plain) and W_x2y with interleaved K
// permute: Wp[y][2j] = W[y][j], Wp[y][2j+1] = W[y][j+128].
// ---------------------------------------------------------------------------
__global__ __launch_bounds__(256) void k_prep(
    const float* __restrict__ B, const float* __restrict__ W,
    const float* __restrict__ y0, const float* __restrict__ Wy2x,
    const float* __restrict__ by2x,
    unsigned short* __restrict__ Bph, unsigned short* __restrict__ Bpl,
    unsigned short* __restrict__ Wph, unsigned short* __restrict__ Wpl,
    float2* __restrict__ x0p)
{
    int bx = blockIdx.x, tid = threadIdx.x;
    if (bx < 32) {
        if (tid < HH) {
            int b = bx, ch = tid;
            float xr = by2x[ch], xi = by2x[ch + HH];
            for (int y = 0; y < NYY; ++y) {
                float v = y0[b * NYY + y];
                xr += v * Wy2x[ch * NYY + y];
                xi += v * Wy2x[(ch + HH) * NYY + y];
            }
            x0p[b * HH + ch] = make_float2(xr, xi);
        }
    } else {
        int i = (bx - 32) * 256 + tid;            // 0..16383
        float bv = B[i];
        __bf16 bh = (__bf16)bv;
        Bph[i] = __builtin_bit_cast(unsigned short, bh);
        Bpl[i] = __builtin_bit_cast(unsigned short, (__bf16)(bv - (float)bh));
        int y = i >> 8, kidx = i & 255;
        float wv = W[y * NHH + (kidx & 1) * HH + (kidx >> 1)];
        __bf16 wh = (__bf16)wv;
        Wph[i] = __builtin_bit_cast(unsigned short, wh);
        Wpl[i] = __builtin_bit_cast(unsigned short, (__bf16)(wv - (float)wh));
    }
}

// ---------------------------------------------------------------------------
// Pass 1: R2's exact proven kernel (record build, verbatim).
// ---------------------------------------------------------------------------
__global__ __launch_bounds__(256, 1) void k_pass1(
    const float* __restrict__ U,
    const unsigned short* __restrict__ Bph, const unsigned short* __restrict__ Bpl,
    const float* __restrict__ lre, const float* __restrict__ lim,
    float2* __restrict__ E)
{
    __shared__ __align__(16) unsigned short sU[2][64 * 136];   // 2 x 17.4 KB

    const int tid = threadIdx.x, w = tid >> 6, lane = tid & 63;
    const int l31 = lane & 31, kh = lane >> 5;
    const int c = blockIdx.x;
    const int ch = w * 32 + l31;

    float lr, li; lam_f32(lre[ch], lim[ch], lr, li);

    bf16x8 bfh[2][4], bfl[2][4];
#pragma unroll
    for (int nt = 0; nt < 2; ++nt)
#pragma unroll
        for (int kk = 0; kk < 4; ++kk) {
            bfh[nt][kk] = ldfrag(&Bph[(size_t)(nt * HH + ch) * NUU + kk * 16 + kh * 8]);
            bfl[nt][kk] = ldfrag(&Bpl[(size_t)(nt * HH + ch) * NUU + kk * 16 + kh * 8]);
        }

    float zr[16], zi[16];
#pragma unroll
    for (int r = 0; r < 16; ++r) { zr[r] = 0.f; zi[r] = 0.f; }

    const int srow = tid >> 2, sus = (tid & 3) * 16;
    const int sb = srow & 31, stoff = srow >> 5;
    const float* ubase = U + (size_t)sb * NUU + sus;

    float4 f0, f1, f2, f3;
    {
        const float4* sp = (const float4*)(ubase + (size_t)(c * LCH + stoff) * (NBB * NUU));
        f0 = sp[0]; f1 = sp[1]; f2 = sp[2]; f3 = sp[3];
    }

    for (int sub = 0; sub < 4; ++sub) {
        unsigned short* su = &sU[sub & 1][0];
        {   // convert staged regs -> split-bf16, write LDS
            bf16x8 h0, h1, l0, l1;
            CVT(f0.x, h0[0], l0[0]); CVT(f0.y, h0[1], l0[1]); CVT(f0.z, h0[2], l0[2]); CVT(f0.w, h0[3], l0[3]);
            CVT(f1.x, h0[4], l0[4]); CVT(f1.y, h0[5], l0[5]); CVT(f1.z, h0[6], l0[6]); CVT(f1.w, h0[7], l0[7]);
            CVT(f2.x, h1[0], l1[0]); CVT(f2.y, h1[1], l1[1]); CVT(f2.z, h1[2], l1[2]); CVT(f2.w, h1[3], l1[3]);
            CVT(f3.x, h1[4], l1[4]); CVT(f3.y, h1[5], l1[5]); CVT(f3.z, h1[6], l1[6]); CVT(f3.w, h1[7], l1[7]);
            *(bf16x8*)&su[srow * 136 + sus]          = h0;
            *(bf16x8*)&su[srow * 136 + sus + 8]      = h1;
            *(bf16x8*)&su[srow * 136 + 64 + sus]     = l0;
            *(bf16x8*)&su[srow * 136 + 64 + sus + 8] = l1;
        }
        __syncthreads();

        if (sub < 3) {   // prefetch next sub while MFMA runs
            const float4* sp = (const float4*)(ubase + (size_t)(c * LCH + (sub + 1) * 2 + stoff) * (NBB * NUU));
            f0 = sp[0]; f1 = sp[1]; f2 = sp[2]; f3 = sp[3];
        }

        f32x16 acc[2][2];
#pragma unroll
        for (int mt = 0; mt < 2; ++mt)
#pragma unroll
            for (int nt = 0; nt < 2; ++nt)
#pragma unroll
                for (int r = 0; r < 16; ++r) acc[mt][nt][r] = 0.f;

#pragma unroll
        for (int kk = 0; kk < 4; ++kk) {
            bf16x8 a0h = ldfrag(&su[(l31)      * 136 + kk * 16 + kh * 8]);
            bf16x8 a1h = ldfrag(&su[(32 + l31) * 136 + kk * 16 + kh * 8]);
            bf16x8 a0l = ldfrag(&su[(l31)      * 136 + 64 + kk * 16 + kh * 8]);
            bf16x8 a1l = ldfrag(&su[(32 + l31) * 136 + 64 + kk * 16 + kh * 8]);
            acc[0][0] = __builtin_amdgcn_mfma_f32_32x32x16_bf16(a0h, bfh[0][kk], acc[0][0], 0, 0, 0);
            acc[0][1] = __builtin_amdgcn_mfma_f32_32x32x16_bf16(a0h, bfh[1][kk], acc[0][1], 0, 0, 0);
            acc[1][0] = __builtin_amdgcn_mfma_f32_32x32x16_bf16(a1h, bfh[0][kk], acc[1][0], 0, 0, 0);
            acc[1][1] = __builtin_amdgcn_mfma_f32_32x32x16_bf16(a1h, bfh[1][kk], acc[1][1], 0, 0, 0);
            acc[0][0] = __builtin_amdgcn_mfma_f32_32x32x16_bf16(a0l, bfh[0][kk], acc[0][0], 0, 0, 0);
            acc[0][1] = __builtin_amdgcn_mfma_f32_32x32x16_bf16(a0l, bfh[1][kk], acc[0][1], 0, 0, 0);
            acc[1][0] = __builtin_amdgcn_mfma_f32_32x32x16_bf16(a1l, bfh[0][kk], acc[1][0], 0, 0, 0);
            acc[1][1] = __builtin_amdgcn_mfma_f32_32x32x16_bf16(a1l, bfh[1][kk], acc[1][1], 0, 0, 0);
            acc[0][0] = __builtin_amdgcn_mfma_f32_32x32x16_bf16(a0h, bfl[0][kk], acc[0][0], 0, 0, 0);
            acc[0][1] = __builtin_amdgcn_mfma_f32_32x32x16_bf16(a0h, bfl[1][kk], acc[0][1], 0, 0, 0);
            acc[1][0] = __builtin_amdgcn_mfma_f32_32x32x16_bf16(a1h, bfl[0][kk], acc[1][0], 0, 0, 0);
            acc[1][1] = __builtin_amdgcn_mfma_f32_32x32x16_bf16(a1h, bfl[1][kk], acc[1][1], 0, 0, 0);
        }

#pragma unroll
        for (int mt = 0; mt < 2; ++mt)
#pragma unroll
            for (int r = 0; r < 16; ++r) {
                float t0 = fmaf(lr, zr[r], acc[mt][0][r]); t0 = fmaf(-li, zi[r], t0);
                float t1 = fmaf(li, zr[r], acc[mt][1][r]); t1 = fmaf(lr, zi[r], t1);
                zr[r] = t0; zi[r] = t1;
            }
        // no trailing barrier: next sub writes the other buffer
    }

#pragma unroll
    for (int r = 0; r < 16; ++r)
        E[(size_t)c * 4096 + crow(r, lane) * HH + ch] = make_float2(zr[r], zi[r]);
}

// ---------------------------------------------------------------------------
// Carry: cseg (f32 chain, R13-validated) + tiny csup (f64, R1-validated).
// The per-chunk expansion is inlined into pass2's prologue (E is L3-hot).
// ---------------------------------------------------------------------------
__global__ __launch_bounds__(256) void k_cseg(
    const float* __restrict__ lre, const float* __restrict__ lim,
    const float2* __restrict__ E, float2* __restrict__ Esup)
{
    int g = blockIdx.x * 256 + threadIdx.x;
    int chain = g & 4095, seg = g >> 12, ch = chain & 127;
    float lrf, lif; lam_f32(lre[ch], lim[ch], lrf, lif);
    double prd = (double)lrf, pid = (double)lif;
#pragma unroll
    for (int s = 0; s < 3; ++s) { double nr = prd*prd - pid*pid, ni = 2.0*prd*pid; prd = nr; pid = ni; } // lambda^8
    float pr = (float)prd, pi = (float)pid;
    float2 e[CPS];
#pragma unroll
    for (int j = 0; j < CPS; ++j)
        e[j] = E[((size_t)seg * CPS + j) * 4096 + chain];
    float sr = 0.f, si = 0.f;
#pragma unroll
    for (int j = 0; j < CPS; ++j) {
        float nr = fmaf(pr, sr, fmaf(-pi, si, e[j].x));
        float ni = fmaf(pi, sr, fmaf(pr, si, e[j].y));
        sr = nr; si = ni;
    }
    Esup[(size_t)seg * 4096 + chain] = make_float2(sr, si);
}

__global__ __launch_bounds__(256) void k_csup(
    const float* __restrict__ lre, const float* __restrict__ lim,
    const float2* __restrict__ x0p, const float2* __restrict__ Esup,
    float2* __restrict__ CarrySup)
{
    int chain = blockIdx.x * 256 + threadIdx.x;   // grid 16 -> 0..4095
    int ch = chain & 127;
    float lrf, lif; lam_f32(lre[ch], lim[ch], lrf, lif);
    double pr = (double)lrf, pi = (double)lif;
#pragma unroll
    for (int s = 0; s < 8; ++s) { double nr = pr*pr - pi*pi, ni = 2.0*pr*pi; pr = nr; pi = ni; } // lambda^256
    float2 es[SEGN - 1];
#pragma unroll
    for (int s = 0; s < SEGN - 1; ++s)
        es[s] = Esup[(size_t)s * 4096 + chain];
    float2 c0 = x0p[chain];
    double cr = (double)c0.x, ci = (double)c0.y;
#pragma unroll
    for (int s = 0; s < SEGN; ++s) {
        CarrySup[(size_t)s * 4096 + chain] = make_float2((float)cr, (float)ci);
        if (s < SEGN - 1) {
            double nr = pr * cr - pi * ci + (double)es[s].x;
            double ni = pi * cr + pr * ci + (double)es[s].y;
            cr = nr; ci = ni;
        }
    }
}

// ---------------------------------------------------------------------------
// Pass 2: R2's measured-best kernel + inlined carry expansion prologue
// (replaces the former k_cexp2 kernel and the 16.8 MB Carry round-trip).
// Seed = CarrySup[c>>5] advanced (c&31) steps with L3-hot E (f32 chain,
// identical math to the R13-validated k_cexp2 expansion).
// ---------------------------------------------------------------------------
__global__ __launch_bounds__(256, 1) void k_pass2(
    const float* __restrict__ U,
    const unsigned short* __restrict__ Bph, const unsigned short* __restrict__ Bpl,
    const unsigned short* __restrict__ Wph, const unsigned short* __restrict__ Wpl,
    const float* __restrict__ lre, const float* __restrict__ lim,
    const float* __restrict__ bx2y,
    const float2* __restrict__ CarrySup, const float2* __restrict__ E,
    float* __restrict__ Y)
{
    __shared__ __align__(16) unsigned short sU[64 * 128];   // 16384 B, swizzled
    __shared__ __align__(16) unsigned short sX[64 * 512];   // 65536 B, swizzled

    const int tid = threadIdx.x, w = tid >> 6, lane = tid & 63;
    const int l31 = lane & 31, kh = lane >> 5;
    const int c = blockIdx.x;
    const int ch = w * 32 + l31;             // scan channel
    const int mtile = w & 1, ntile = w >> 1; // out-GEMM tile mapping

    float lr, li; lam_f32(lre[ch], lim[ch], lr, li);
    float ybias = bx2y[ntile * 32 + l31];

    // ---- inlined carry expansion (was k_cexp2) ----
    float zr[16], zi[16];
    {
        const int seg = c >> 5, off = c & 31;
        double p8r = (double)lr, p8i = (double)li;
#pragma unroll
        for (int s = 0; s < 3; ++s) { double nr = p8r*p8r - p8i*p8i, ni = 2.0*p8r*p8i; p8r = nr; p8i = ni; } // lambda^8
        float l8r = (float)p8r, l8i = (float)p8i;
#pragma unroll
        for (int r = 0; r < 16; ++r) {
            float2 v = CarrySup[(size_t)seg * 4096 + crow(r, lane) * HH + ch];
            zr[r] = v.x; zi[r] = v.y;
        }
        for (int j = 0; j < off; ++j) {
            float2 e[16];
#pragma unroll
            for (int r = 0; r < 16; ++r)
                e[r] = E[((size_t)(seg * CPS + j)) * 4096 + crow(r, lane) * HH + ch];
#pragma unroll
            for (int r = 0; r < 16; ++r) {
                float nr = fmaf(l8r, zr[r], fmaf(-l8i, zi[r], e[r].x));
                float ni = fmaf(l8i, zr[r], fmaf(l8r, zi[r], e[r].y));
                zr[r] = nr; zi[r] = ni;
            }
        }
    }

    bf16x8 bfh[2][4], bfl[2][4];
#pragma unroll
    for (int nt = 0; nt < 2; ++nt)
#pragma unroll
        for (int kk = 0; kk < 4; ++kk) {
            bfh[nt][kk] = ldfrag(&Bph[(size_t)(nt * HH + ch) * NUU + kk * 16 + kh * 8]);
            bfl[nt][kk] = ldfrag(&Bpl[(size_t)(nt * HH + ch) * NUU + kk * 16 + kh * 8]);
        }

    bf16x8 wfh[16], wfl[16];
#pragma unroll
    for (int kk = 0; kk < 16; ++kk) {
        wfh[kk] = ldfrag(&Wph[(size_t)(ntile * 32 + l31) * NHH + kk * 16 + kh * 8]);
        wfl[kk] = ldfrag(&Wpl[(size_t)(ntile * 32 + l31) * NHH + kk * 16 + kh * 8]);
    }

    const int srow = tid >> 2, sus = (tid & 3) * 16;
    const int sb = srow & 31, stoff = srow >> 5;
    const float* ubase = U + (size_t)sb * NUU + sus;

    float4 f0, f1, f2, f3;
    {
        const float4* sp = (const float4*)(ubase + (size_t)(c * LCH + stoff) * (NBB * NUU));
        f0 = sp[0]; f1 = sp[1]; f2 = sp[2]; f3 = sp[3];
    }

    for (int sub = 0; sub < 4; ++sub) {
        {   // convert + write sU (swizzled)
            bf16x8 h0, h1, l0, l1;
            CVT(f0.x, h0[0], l0[0]); CVT(f0.y, h0[1], l0[1]); CVT(f0.z, h0[2], l0[2]); CVT(f0.w, h0[3], l0[3]);
            CVT(f1.x, h0[4], l0[4]); CVT(f1.y, h0[5], l0[5]); CVT(f1.z, h0[6], l0[6]); CVT(f1.w, h0[7], l0[7]);
            CVT(f2.x, h1[0], l1[0]); CVT(f2.y, h1[1], l1[1]); CVT(f2.z, h1[2], l1[2]); CVT(f2.w, h1[3], l1[3]);
            CVT(f3.x, h1[4], l1[4]); CVT(f3.y, h1[5], l1[5]); CVT(f3.z, h1[6], l1[6]); CVT(f3.w, h1[7], l1[7]);
            *(bf16x8*)&sU[swzU(srow, sus)]          = h0;
            *(bf16x8*)&sU[swzU(srow, sus + 8)]      = h1;
            *(bf16x8*)&sU[swzU(srow, 64 + sus)]     = l0;
            *(bf16x8*)&sU[swzU(srow, 64 + sus + 8)] = l1;
        }

        if (sub > 0) {  // out-GEMM for sub-1 (reads sX written before last barrier)
            f32x16 ya0, ya1, ya2;
#pragma unroll
            for (int r = 0; r < 16; ++r) { ya0[r] = 0.f; ya1[r] = 0.f; ya2[r] = 0.f; }
#pragma unroll
            for (int kk = 0; kk < 16; ++kk) {
                bf16x8 xah = ldfrag(&sX[swzX(mtile * 32 + l31, kk * 16 + kh * 8)]);
                bf16x8 xal = ldfrag(&sX[swzX(mtile * 32 + l31, 256 + kk * 16 + kh * 8)]);
                ya0 = __builtin_amdgcn_mfma_f32_32x32x16_bf16(xah, wfh[kk], ya0, 0, 0, 0);
                ya1 = __builtin_amdgcn_mfma_f32_32x32x16_bf16(xal, wfh[kk], ya1, 0, 0, 0);
                ya2 = __builtin_amdgcn_mfma_f32_32x32x16_bf16(xah, wfl[kk], ya2, 0, 0, 0);
            }
            int t = c * LCH + (sub - 1) * 2 + mtile;
#pragma unroll
            for (int r = 0; r < 16; ++r)
                Y[((size_t)t * NBB + crow(r, lane)) * NYY + ntile * 32 + l31] =
                    (ya0[r] + ya1[r]) + ya2[r] + ybias;
        }
        __syncthreads();

        if (sub < 3) {   // prefetch next sub; lands under the MFMA phase
            const float4* sp = (const float4*)(ubase + (size_t)(c * LCH + (sub + 1) * 2 + stoff) * (NBB * NUU));
            f0 = sp[0]; f1 = sp[1]; f2 = sp[2]; f3 = sp[3];
        }

        // Bu MFMA (split 3-term)
        f32x16 acc[2][2];
#pragma unroll
        for (int mt = 0; mt < 2; ++mt)
#pragma unroll
            for (int nt = 0; nt < 2; ++nt)
#pragma unroll
                for (int r = 0; r < 16; ++r) acc[mt][nt][r] = 0.f;

#pragma unroll
        for (int kk = 0; kk < 4; ++kk) {
            bf16x8 a0h = ldfrag(&sU[swzU(l31,      kk * 16 + kh * 8)]);
            bf16x8 a1h = ldfrag(&sU[swzU(32 + l31, kk * 16 + kh * 8)]);
            bf16x8 a0l = ldfrag(&sU[swzU(l31,      64 + kk * 16 + kh * 8)]);
            bf16x8 a1l = ldfrag(&sU[swzU(32 + l31, 64 + kk * 16 + kh * 8)]);
            acc[0][0] = __builtin_amdgcn_mfma_f32_32x32x16_bf16(a0h, bfh[0][kk], acc[0][0], 0, 0, 0);
            acc[0][1] = __builtin_amdgcn_mfma_f32_32x32x16_bf16(a0h, bfh[1][kk], acc[0][1], 0, 0, 0);
            acc[1][0] = __builtin_amdgcn_mfma_f32_32x32x16_bf16(a1h, bfh[0][kk], acc[1][0], 0, 0, 0);
            acc[1][1] = __builtin_amdgcn_mfma_f32_32x32x16_bf16(a1h, bfh[1][kk], acc[1][1], 0, 0, 0);
            acc[0][0] = __builtin_amdgcn_mfma_f32_32x32x16_bf16(a0l, bfh[0][kk], acc[0][0], 0, 0, 0);
            acc[0][1] = __builtin_amdgcn_mfma_f32_32x32x16_bf16(a0l, bfh[1][kk], acc[0][1], 0, 0, 0);
            acc[1][0] = __builtin_amdgcn_mfma_f32_32x32x16_bf16(a1l, bfh[0][kk], acc[1][0], 0, 0, 0);
            acc[1][1] = __builtin_amdgcn_mfma_f32_32x32x16_bf16(a1l, bfh[1][kk], acc[1][1], 0, 0, 0);
            acc[0][0] = __builtin_amdgcn_mfma_f32_32x32x16_bf16(a0h, bfl[0][kk], acc[0][0], 0, 0, 0);
            acc[0][1] = __builtin_amdgcn_mfma_f32_32x32x16_bf16(a0h, bfl[1][kk], acc[0][1], 0, 0, 0);
            acc[1][0] = __builtin_amdgcn_mfma_f32_32x32x16_bf16(a1h, bfl[0][kk], acc[1][0], 0, 0, 0);
            acc[1][1] = __builtin_amdgcn_mfma_f32_32x32x16_bf16(a1h, bfl[1][kk], acc[1][1], 0, 0, 0);
        }

        // Scan + split hi/lo dump (two b32 per (mt,r)), swizzled
#pragma unroll
        for (int mt = 0; mt < 2; ++mt)
#pragma unroll
            for (int r = 0; r < 16; ++r) {
                float t0 = fmaf(lr, zr[r], acc[mt][0][r]); t0 = fmaf(-li, zi[r], t0);
                float t1 = fmaf(li, zr[r], acc[mt][1][r]); t1 = fmaf(lr, zi[r], t1);
                zr[r] = t0; zi[r] = t1;
                bf16x2 hv, lv;
                { __bf16 _h = (__bf16)t0; hv[0] = _h; lv[0] = (__bf16)(t0 - (float)_h); }
                { __bf16 _h = (__bf16)t1; hv[1] = _h; lv[1] = (__bf16)(t1 - (float)_h); }
                int row = mt * 32 + crow(r, lane);
                *(bf16x2*)&sX[swzX(row, w * 64 + 2 * l31)]       = hv;
                *(bf16x2*)&sX[swzX(row, 256 + w * 64 + 2 * l31)] = lv;
            }
        __syncthreads();
    }

    // Drain: out-GEMM for sub=3
    {
        f32x16 ya0, ya1, ya2;
#pragma unroll
        for (int r = 0; r < 16; ++r) { ya0[r] = 0.f; ya1[r] = 0.f; ya2[r] = 0.f; }
#pragma unroll
        for (int kk = 0; kk < 16; ++kk) {
            bf16x8 xah = ldfrag(&sX[swzX(mtile * 32 + l31, kk * 16 + kh * 8)]);
            bf16x8 xal = ldfrag(&sX[swzX(mtile * 32 + l31, 256 + kk * 16 + kh * 8)]);
            ya0 = __builtin_amdgcn_mfma_f32_32x32x16_bf16(xah, wfh[kk], ya0, 0, 0, 0);
            ya1 = __builtin_amdgcn_mfma_f32_32x32x16_bf16(xal, wfh[kk], ya1, 0, 0, 0);
            ya2 = __builtin_amdgcn_mfma_f32_32x32x16_bf16(xah, wfl[kk], ya2, 0, 0, 0);
        }
        int t = c * LCH + 3 * 2 + mtile;
#pragma unroll
        for (int r = 0; r < 16; ++r)
            Y[((size_t)t * NBB + crow(r, lane)) * NYY + ntile * 32 + l31] =
                (ya0[r] + ya1[r]) + ya2[r] + ybias;
    }
}

// ---------------------------------------------------------------------------
extern "C" void kernel_launch(void* const* d_in, const int* in_sizes, int n_in,
                              void* d_out, int out_size, void* d_ws, size_t ws_size,
                              hipStream_t stream) {
    const float* y0    = (const float*)d_in[0];
    const float* U     = (const float*)d_in[1];
    const float* lre   = (const float*)d_in[2];
    const float* lim   = (const float*)d_in[3];
    const float* B     = (const float*)d_in[4];
    const float* W_y2x = (const float*)d_in[5];
    const float* b_y2x = (const float*)d_in[6];
    const float* W_x2y = (const float*)d_in[7];
    const float* b_x2y = (const float*)d_in[8];
    float* Y = (float*)d_out;

    char* p = (char*)d_ws;
    float2* E        = (float2*)p; p += (size_t)CCH * 4096 * sizeof(float2);   // 16.8 MB
    float2* Esup     = (float2*)p; p += (size_t)SEGN * 4096 * sizeof(float2);  // 512 KB
    float2* CarrySup = (float2*)p; p += (size_t)SEGN * 4096 * sizeof(float2);  // 512 KB
    float2* x0p      = (float2*)p; p += (size_t)4096 * sizeof(float2);         // 32 KB
    unsigned short* Bph = (unsigned short*)p; p += 16384 * sizeof(unsigned short);
    unsigned short* Bpl = (unsigned short*)p; p += 16384 * sizeof(unsigned short);
    unsigned short* Wph = (unsigned short*)p; p += 16384 * sizeof(unsigned short);
    unsigned short* Wpl = (unsigned short*)p; p += 16384 * sizeof(unsigned short);

    k_prep <<<dim3(96),  dim3(256), 0, stream>>>(B, W_x2y, y0, W_y2x, b_y2x, Bph, Bpl, Wph, Wpl, x0p);
    k_pass1<<<dim3(CCH), dim3(256), 0, stream>>>(U, Bph, Bpl, lre, lim, E);
    k_cseg <<<dim3(256), dim3(256), 0, stream>>>(lre, lim, E, Esup);
    k_csup <<<dim3(16),  dim3(256), 0, stream>>>(lre, lim, x0p, Esup, CarrySup);
    k_pass2<<<dim3(CCH), dim3(256), 0, stream>>>(U, Bph, Bpl, Wph, Wpl, lre, lim, b_x2y, CarrySup, E, Y);
}

// Round 15
// 160.092 us; speedup vs baseline: 1.2368x; 1.2368x over previous
//
#include <hip/hip_runtime.h>
#include <math.h>

// Problem constants
#define TT   4096
#define NBB  32
#define NUU  64
#define NHH  256
#define HH   128
#define NYY  64
// Chunking: 256 chunks of 16 steps; carry hierarchy: 8 supers x 32 chunks
#define LCH  16
#define CCH  256
#define SEGN 8
#define CPS  32

#define PI_HALF 1.5707963267948966f

typedef float  f32x16 __attribute__((ext_vector_type(16)));
typedef __bf16 bf16x8 __attribute__((ext_vector_type(8)));
typedef __bf16 bf16x2 __attribute__((ext_vector_type(2)));
typedef unsigned int uint4v __attribute__((ext_vector_type(4)));

// MFMA 32x32 C/D layout: row = (r&3) + 8*(r>>2) + 4*(lane>>5), col = lane&31
__device__ inline int crow(int r, int lane) { return (r & 3) + 8 * (r >> 2) + 4 * (lane >> 5); }
__device__ inline bf16x8 ldfrag(const unsigned short* p) {
    return __builtin_bit_cast(bf16x8, *(const uint4v*)p);
}

// split a float into bf16 hi + bf16 lo (hi+lo ~ exact to 2^-17 rel)
#define CVT(v, H, L) { __bf16 _h = (__bf16)(v); H = _h; L = (__bf16)((v) - (float)_h); }

// lambda in fp32 with correctly-rounded transcendentals (double -> fp32)
__device__ inline void lam_f32(float xre, float xim, float& lr, float& li) {
    float th = PI_HALF * xim;
    float rf = (float)exp(-(double)fabsf(xre));
    float cf = (float)cos((double)th);
    float sf = (float)sin((double)th);
    lr = rf * cf; li = rf * sf;
}

// --- swizzled LDS index helpers for pass2 (offsets in shorts) -------------
// pass2 sU (64 rows x 128): 16B chunk ^= row&15
__device__ inline int swzU(int row, int so) {
    return row * 128 + ((((so >> 3) ^ row) & 15) << 3) + (so & 7);
}
// pass2 sX (64 rows x 512): low-5 of chunk ^= row, bit5 kept
__device__ inline int swzX(int row, int so) {
    int chv = so >> 3;
    chv = (chv & 32) | ((chv ^ row) & 31);
    return row * 512 + (chv << 3) + (so & 7);
}

// ---------------------------------------------------------------------------
// Prep: x0 pairs; bf16 hi/lo split of B (plain) and W_x2y with interleaved K
// permute: Wp[y][2j] = W[y][j], Wp[y][2j+1] = W[y][j+128].
// ---------------------------------------------------------------------------
__global__ __launch_bounds__(256) void k_prep(
    const float* __restrict__ B, const float* __restrict__ W,
    const float* __restrict__ y0, const float* __restrict__ Wy2x,
    const float* __restrict__ by2x,
    unsigned short* __restrict__ Bph, unsigned short* __restrict__ Bpl,
    unsigned short* __restrict__ Wph, unsigned short* __restrict__ Wpl,
    float2* __restrict__ x0p)
{
    int bx = blockIdx.x, tid = threadIdx.x;
    if (bx < 32) {
        if (tid < HH) {
            int b = bx, ch = tid;
            float xr = by2x[ch], xi = by2x[ch + HH];
            for (int y = 0; y < NYY; ++y) {
                float v = y0[b * NYY + y];
                xr += v * Wy2x[ch * NYY + y];
                xi += v * Wy2x[(ch + HH) * NYY + y];
            }
            x0p[b * HH + ch] = make_float2(xr, xi);
        }
    } else {
        int i = (bx - 32) * 256 + tid;            // 0..16383
        float bv = B[i];
        __bf16 bh = (__bf16)bv;
        Bph[i] = __builtin_bit_cast(unsigned short, bh);
        Bpl[i] = __builtin_bit_cast(unsigned short, (__bf16)(bv - (float)bh));
        int y = i >> 8, kidx = i & 255;
        float wv = W[y * NHH + (kidx & 1) * HH + (kidx >> 1)];
        __bf16 wh = (__bf16)wv;
        Wph[i] = __builtin_bit_cast(unsigned short, wh);
        Wpl[i] = __builtin_bit_cast(unsigned short, (__bf16)(wv - (float)wh));
    }
}

// ---------------------------------------------------------------------------
// Pass 1: frozen R2 inner structure; sub loop now runs LCH/2 = 8 iterations
// (16-step chunks). Grid 256 = exactly 1 block/CU.
// ---------------------------------------------------------------------------
__global__ __launch_bounds__(256, 1) void k_pass1(
    const float* __restrict__ U,
    const unsigned short* __restrict__ Bph, const unsigned short* __restrict__ Bpl,
    const float* __restrict__ lre, const float* __restrict__ lim,
    float2* __restrict__ E)
{
    __shared__ __align__(16) unsigned short sU[2][64 * 136];   // 2 x 17.4 KB

    const int tid = threadIdx.x, w = tid >> 6, lane = tid & 63;
    const int l31 = lane & 31, kh = lane >> 5;
    const int c = blockIdx.x;
    const int ch = w * 32 + l31;

    float lr, li; lam_f32(lre[ch], lim[ch], lr, li);

    bf16x8 bfh[2][4], bfl[2][4];
#pragma unroll
    for (int nt = 0; nt < 2; ++nt)
#pragma unroll
        for (int kk = 0; kk < 4; ++kk) {
            bfh[nt][kk] = ldfrag(&Bph[(size_t)(nt * HH + ch) * NUU + kk * 16 + kh * 8]);
            bfl[nt][kk] = ldfrag(&Bpl[(size_t)(nt * HH + ch) * NUU + kk * 16 + kh * 8]);
        }

    float zr[16], zi[16];
#pragma unroll
    for (int r = 0; r < 16; ++r) { zr[r] = 0.f; zi[r] = 0.f; }

    const int srow = tid >> 2, sus = (tid & 3) * 16;
    const int sb = srow & 31, stoff = srow >> 5;
    const float* ubase = U + (size_t)sb * NUU + sus;

    float4 f0, f1, f2, f3;
    {
        const float4* sp = (const float4*)(ubase + (size_t)(c * LCH + stoff) * (NBB * NUU));
        f0 = sp[0]; f1 = sp[1]; f2 = sp[2]; f3 = sp[3];
    }

    for (int sub = 0; sub < LCH / 2; ++sub) {
        unsigned short* su = &sU[sub & 1][0];
        {   // convert staged regs -> split-bf16, write LDS
            bf16x8 h0, h1, l0, l1;
            CVT(f0.x, h0[0], l0[0]); CVT(f0.y, h0[1], l0[1]); CVT(f0.z, h0[2], l0[2]); CVT(f0.w, h0[3], l0[3]);
            CVT(f1.x, h0[4], l0[4]); CVT(f1.y, h0[5], l0[5]); CVT(f1.z, h0[6], l0[6]); CVT(f1.w, h0[7], l0[7]);
            CVT(f2.x, h1[0], l1[0]); CVT(f2.y, h1[1], l1[1]); CVT(f2.z, h1[2], l1[2]); CVT(f2.w, h1[3], l1[3]);
            CVT(f3.x, h1[4], l1[4]); CVT(f3.y, h1[5], l1[5]); CVT(f3.z, h1[6], l1[6]); CVT(f3.w, h1[7], l1[7]);
            *(bf16x8*)&su[srow * 136 + sus]          = h0;
            *(bf16x8*)&su[srow * 136 + sus + 8]      = h1;
            *(bf16x8*)&su[srow * 136 + 64 + sus]     = l0;
            *(bf16x8*)&su[srow * 136 + 64 + sus + 8] = l1;
        }
        __syncthreads();

        if (sub < LCH / 2 - 1) {   // prefetch next sub while MFMA runs
            const float4* sp = (const float4*)(ubase + (size_t)(c * LCH + (sub + 1) * 2 + stoff) * (NBB * NUU));
            f0 = sp[0]; f1 = sp[1]; f2 = sp[2]; f3 = sp[3];
        }

        f32x16 acc[2][2];
#pragma unroll
        for (int mt = 0; mt < 2; ++mt)
#pragma unroll
            for (int nt = 0; nt < 2; ++nt)
#pragma unroll
                for (int r = 0; r < 16; ++r) acc[mt][nt][r] = 0.f;

#pragma unroll
        for (int kk = 0; kk < 4; ++kk) {
            bf16x8 a0h = ldfrag(&su[(l31)      * 136 + kk * 16 + kh * 8]);
            bf16x8 a1h = ldfrag(&su[(32 + l31) * 136 + kk * 16 + kh * 8]);
            bf16x8 a0l = ldfrag(&su[(l31)      * 136 + 64 + kk * 16 + kh * 8]);
            bf16x8 a1l = ldfrag(&su[(32 + l31) * 136 + 64 + kk * 16 + kh * 8]);
            acc[0][0] = __builtin_amdgcn_mfma_f32_32x32x16_bf16(a0h, bfh[0][kk], acc[0][0], 0, 0, 0);
            acc[0][1] = __builtin_amdgcn_mfma_f32_32x32x16_bf16(a0h, bfh[1][kk], acc[0][1], 0, 0, 0);
            acc[1][0] = __builtin_amdgcn_mfma_f32_32x32x16_bf16(a1h, bfh[0][kk], acc[1][0], 0, 0, 0);
            acc[1][1] = __builtin_amdgcn_mfma_f32_32x32x16_bf16(a1h, bfh[1][kk], acc[1][1], 0, 0, 0);
            acc[0][0] = __builtin_amdgcn_mfma_f32_32x32x16_bf16(a0l, bfh[0][kk], acc[0][0], 0, 0, 0);
            acc[0][1] = __builtin_amdgcn_mfma_f32_32x32x16_bf16(a0l, bfh[1][kk], acc[0][1], 0, 0, 0);
            acc[1][0] = __builtin_amdgcn_mfma_f32_32x32x16_bf16(a1l, bfh[0][kk], acc[1][0], 0, 0, 0);
            acc[1][1] = __builtin_amdgcn_mfma_f32_32x32x16_bf16(a1l, bfh[1][kk], acc[1][1], 0, 0, 0);
            acc[0][0] = __builtin_amdgcn_mfma_f32_32x32x16_bf16(a0h, bfl[0][kk], acc[0][0], 0, 0, 0);
            acc[0][1] = __builtin_amdgcn_mfma_f32_32x32x16_bf16(a0h, bfl[1][kk], acc[0][1], 0, 0, 0);
            acc[1][0] = __builtin_amdgcn_mfma_f32_32x32x16_bf16(a1h, bfl[0][kk], acc[1][0], 0, 0, 0);
            acc[1][1] = __builtin_amdgcn_mfma_f32_32x32x16_bf16(a1h, bfl[1][kk], acc[1][1], 0, 0, 0);
        }

#pragma unroll
        for (int mt = 0; mt < 2; ++mt)
#pragma unroll
            for (int r = 0; r < 16; ++r) {
                float t0 = fmaf(lr, zr[r], acc[mt][0][r]); t0 = fmaf(-li, zi[r], t0);
                float t1 = fmaf(li, zr[r], acc[mt][1][r]); t1 = fmaf(lr, zi[r], t1);
                zr[r] = t0; zi[r] = t1;
            }
        // no trailing barrier: next sub writes the other buffer
    }

#pragma unroll
    for (int r = 0; r < 16; ++r)
        E[(size_t)c * 4096 + crow(r, lane) * HH + ch] = make_float2(zr[r], zi[r]);
}

// ---------------------------------------------------------------------------
// Carry hierarchy (R13-validated forms, adapted to lambda^16 chunks):
// cseg: 32-chunk f32 chain per segment; cexp2: f64 super-prefix (lambda^512)
// + 32-step f32 expansion writing Carry.
// ---------------------------------------------------------------------------
__global__ __launch_bounds__(256) void k_cseg(
    const float* __restrict__ lre, const float* __restrict__ lim,
    const float2* __restrict__ E, float2* __restrict__ Esup)
{
    int g = blockIdx.x * 256 + threadIdx.x;      // grid 128 -> 0..32767
    int chain = g & 4095, seg = g >> 12, ch = chain & 127;
    float lrf, lif; lam_f32(lre[ch], lim[ch], lrf, lif);
    double prd = (double)lrf, pid = (double)lif;
#pragma unroll
    for (int s = 0; s < 4; ++s) { double nr = prd*prd - pid*pid, ni = 2.0*prd*pid; prd = nr; pid = ni; } // lambda^16
    float pr = (float)prd, pi = (float)pid;
    float2 e[CPS];
#pragma unroll
    for (int j = 0; j < CPS; ++j)
        e[j] = E[((size_t)seg * CPS + j) * 4096 + chain];
    float sr = 0.f, si = 0.f;
#pragma unroll
    for (int j = 0; j < CPS; ++j) {
        float nr = fmaf(pr, sr, fmaf(-pi, si, e[j].x));
        float ni = fmaf(pi, sr, fmaf(pr, si, e[j].y));
        sr = nr; si = ni;
    }
    Esup[(size_t)seg * 4096 + chain] = make_float2(sr, si);
}

__global__ __launch_bounds__(256) void k_cexp2(
    const float* __restrict__ lre, const float* __restrict__ lim,
    const float2* __restrict__ x0p, const float2* __restrict__ Esup,
    const float2* __restrict__ E, float2* __restrict__ Carry)
{
    int g = blockIdx.x * 256 + threadIdx.x;      // grid 128
    int chain = g & 4095, seg = g >> 12, ch = chain & 127;
    float lrf, lif; lam_f32(lre[ch], lim[ch], lrf, lif);
    double p16r = (double)lrf, p16i = (double)lif;
#pragma unroll
    for (int s = 0; s < 4; ++s) { double nr = p16r*p16r - p16i*p16i, ni = 2.0*p16r*p16i; p16r = nr; p16i = ni; } // lambda^16
    double pr = p16r, pi = p16i;
#pragma unroll
    for (int s = 0; s < 5; ++s) { double nr = pr*pr - pi*pi, ni = 2.0*pr*pi; pr = nr; pi = ni; } // lambda^512
    // super-prefix in f64
    float2 es[SEGN - 1];
#pragma unroll
    for (int s = 0; s < SEGN - 1; ++s)
        es[s] = Esup[(size_t)s * 4096 + chain];
    float2 c0 = x0p[chain];
    double crd = (double)c0.x, cid = (double)c0.y;
#pragma unroll
    for (int s = 0; s < SEGN - 1; ++s) {
        if (s < seg) {
            double nr = pr * crd - pi * cid + (double)es[s].x;
            double ni = pi * crd + pr * cid + (double)es[s].y;
            crd = nr; cid = ni;
        }
    }
    // expansion within segment: f32 chain (<=32 dependent steps)
    float l16r = (float)p16r, l16i = (float)p16i;
    float cr = (float)crd, ci = (float)cid;
    float2 e[CPS];
#pragma unroll
    for (int j = 0; j < CPS; ++j)
        e[j] = E[((size_t)seg * CPS + j) * 4096 + chain];
#pragma unroll
    for (int j = 0; j < CPS; ++j) {
        Carry[((size_t)seg * CPS + j) * 4096 + chain] = make_float2(cr, ci);
        float nr = fmaf(l16r, cr, fmaf(-l16i, ci, e[j].x));
        float ni = fmaf(l16i, cr, fmaf(l16r, ci, e[j].y));
        cr = nr; ci = ni;
    }
}

// ---------------------------------------------------------------------------
// Pass 2: frozen R2 inner structure; sub loop now LCH/2 = 8 iterations.
// LDS = 16384 (sU swz) + 65536 (sX swz) = 81920 B; (256,1); VGPR 256.
// ---------------------------------------------------------------------------
__global__ __launch_bounds__(256, 1) void k_pass2(
    const float* __restrict__ U,
    const unsigned short* __restrict__ Bph, const unsigned short* __restrict__ Bpl,
    const unsigned short* __restrict__ Wph, const unsigned short* __restrict__ Wpl,
    const float* __restrict__ lre, const float* __restrict__ lim,
    const float* __restrict__ bx2y,
    const float2* __restrict__ Carry, float* __restrict__ Y)
{
    __shared__ __align__(16) unsigned short sU[64 * 128];   // 16384 B, swizzled
    __shared__ __align__(16) unsigned short sX[64 * 512];   // 65536 B, swizzled

    const int tid = threadIdx.x, w = tid >> 6, lane = tid & 63;
    const int l31 = lane & 31, kh = lane >> 5;
    const int c = blockIdx.x;
    const int ch = w * 32 + l31;             // scan channel
    const int mtile = w & 1, ntile = w >> 1; // out-GEMM tile mapping

    float lr, li; lam_f32(lre[ch], lim[ch], lr, li);
    float ybias = bx2y[ntile * 32 + l31];

    bf16x8 bfh[2][4], bfl[2][4];
#pragma unroll
    for (int nt = 0; nt < 2; ++nt)
#pragma unroll
        for (int kk = 0; kk < 4; ++kk) {
            bfh[nt][kk] = ldfrag(&Bph[(size_t)(nt * HH + ch) * NUU + kk * 16 + kh * 8]);
            bfl[nt][kk] = ldfrag(&Bpl[(size_t)(nt * HH + ch) * NUU + kk * 16 + kh * 8]);
        }

    bf16x8 wfh[16], wfl[16];
#pragma unroll
    for (int kk = 0; kk < 16; ++kk) {
        wfh[kk] = ldfrag(&Wph[(size_t)(ntile * 32 + l31) * NHH + kk * 16 + kh * 8]);
        wfl[kk] = ldfrag(&Wpl[(size_t)(ntile * 32 + l31) * NHH + kk * 16 + kh * 8]);
    }

    float zr[16], zi[16];
#pragma unroll
    for (int r = 0; r < 16; ++r) {
        float2 v = Carry[(size_t)c * 4096 + crow(r, lane) * HH + ch];
        zr[r] = v.x; zi[r] = v.y;
    }

    const int srow = tid >> 2, sus = (tid & 3) * 16;
    const int sb = srow & 31, stoff = srow >> 5;
    const float* ubase = U + (size_t)sb * NUU + sus;

    float4 f0, f1, f2, f3;
    {
        const float4* sp = (const float4*)(ubase + (size_t)(c * LCH + stoff) * (NBB * NUU));
        f0 = sp[0]; f1 = sp[1]; f2 = sp[2]; f3 = sp[3];
    }

    for (int sub = 0; sub < LCH / 2; ++sub) {
        {   // convert + write sU (swizzled)
            bf16x8 h0, h1, l0, l1;
            CVT(f0.x, h0[0], l0[0]); CVT(f0.y, h0[1], l0[1]); CVT(f0.z, h0[2], l0[2]); CVT(f0.w, h0[3], l0[3]);
            CVT(f1.x, h0[4], l0[4]); CVT(f1.y, h0[5], l0[5]); CVT(f1.z, h0[6], l0[6]); CVT(f1.w, h0[7], l0[7]);
            CVT(f2.x, h1[0], l1[0]); CVT(f2.y, h1[1], l1[1]); CVT(f2.z, h1[2], l1[2]); CVT(f2.w, h1[3], l1[3]);
            CVT(f3.x, h1[4], l1[4]); CVT(f3.y, h1[5], l1[5]); CVT(f3.z, h1[6], l1[6]); CVT(f3.w, h1[7], l1[7]);
            *(bf16x8*)&sU[swzU(srow, sus)]          = h0;
            *(bf16x8*)&sU[swzU(srow, sus + 8)]      = h1;
            *(bf16x8*)&sU[swzU(srow, 64 + sus)]     = l0;
            *(bf16x8*)&sU[swzU(srow, 64 + sus + 8)] = l1;
        }

        if (sub > 0) {  // out-GEMM for sub-1 (reads sX written before last barrier)
            f32x16 ya0, ya1, ya2;
#pragma unroll
            for (int r = 0; r < 16; ++r) { ya0[r] = 0.f; ya1[r] = 0.f; ya2[r] = 0.f; }
#pragma unroll
            for (int kk = 0; kk < 16; ++kk) {
                bf16x8 xah = ldfrag(&sX[swzX(mtile * 32 + l31, kk * 16 + kh * 8)]);
                bf16x8 xal = ldfrag(&sX[swzX(mtile * 32 + l31, 256 + kk * 16 + kh * 8)]);
                ya0 = __builtin_amdgcn_mfma_f32_32x32x16_bf16(xah, wfh[kk], ya0, 0, 0, 0);
                ya1 = __builtin_amdgcn_mfma_f32_32x32x16_bf16(xal, wfh[kk], ya1, 0, 0, 0);
                ya2 = __builtin_amdgcn_mfma_f32_32x32x16_bf16(xah, wfl[kk], ya2, 0, 0, 0);
            }
            int t = c * LCH + (sub - 1) * 2 + mtile;
#pragma unroll
            for (int r = 0; r < 16; ++r)
                Y[((size_t)t * NBB + crow(r, lane)) * NYY + ntile * 32 + l31] =
                    (ya0[r] + ya1[r]) + ya2[r] + ybias;
        }
        __syncthreads();

        if (sub < LCH / 2 - 1) {   // prefetch next sub; lands under the MFMA phase
            const float4* sp = (const float4*)(ubase + (size_t)(c * LCH + (sub + 1) * 2 + stoff) * (NBB * NUU));
            f0 = sp[0]; f1 = sp[1]; f2 = sp[2]; f3 = sp[3];
        }

        // Bu MFMA (split 3-term)
        f32x16 acc[2][2];
#pragma unroll
        for (int mt = 0; mt < 2; ++mt)
#pragma unroll
            for (int nt = 0; nt < 2; ++nt)
#pragma unroll
                for (int r = 0; r < 16; ++r) acc[mt][nt][r] = 0.f;

#pragma unroll
        for (int kk = 0; kk < 4; ++kk) {
            bf16x8 a0h = ldfrag(&sU[swzU(l31,      kk * 16 + kh * 8)]);
            bf16x8 a1h = ldfrag(&sU[swzU(32 + l31, kk * 16 + kh * 8)]);
            bf16x8 a0l = ldfrag(&sU[swzU(l31,      64 + kk * 16 + kh * 8)]);
            bf16x8 a1l = ldfrag(&sU[swzU(32 + l31, 64 + kk * 16 + kh * 8)]);
            acc[0][0] = __builtin_amdgcn_mfma_f32_32x32x16_bf16(a0h, bfh[0][kk], acc[0][0], 0, 0, 0);
            acc[0][1] = __builtin_amdgcn_mfma_f32_32x32x16_bf16(a0h, bfh[1][kk], acc[0][1], 0, 0, 0);
            acc[1][0] = __builtin_amdgcn_mfma_f32_32x32x16_bf16(a1h, bfh[0][kk], acc[1][0], 0, 0, 0);
            acc[1][1] = __builtin_amdgcn_mfma_f32_32x32x16_bf16(a1h, bfh[1][kk], acc[1][1], 0, 0, 0);
            acc[0][0] = __builtin_amdgcn_mfma_f32_32x32x16_bf16(a0l, bfh[0][kk], acc[0][0], 0, 0, 0);
            acc[0][1] = __builtin_amdgcn_mfma_f32_32x32x16_bf16(a0l, bfh[1][kk], acc[0][1], 0, 0, 0);
            acc[1][0] = __builtin_amdgcn_mfma_f32_32x32x16_bf16(a1l, bfh[0][kk], acc[1][0], 0, 0, 0);
            acc[1][1] = __builtin_amdgcn_mfma_f32_32x32x16_bf16(a1l, bfh[1][kk], acc[1][1], 0, 0, 0);
            acc[0][0] = __builtin_amdgcn_mfma_f32_32x32x16_bf16(a0h, bfl[0][kk], acc[0][0], 0, 0, 0);
            acc[0][1] = __builtin_amdgcn_mfma_f32_32x32x16_bf16(a0h, bfl[1][kk], acc[0][1], 0, 0, 0);
            acc[1][0] = __builtin_amdgcn_mfma_f32_32x32x16_bf16(a1h, bfl[0][kk], acc[1][0], 0, 0, 0);
            acc[1][1] = __builtin_amdgcn_mfma_f32_32x32x16_bf16(a1h, bfl[1][kk], acc[1][1], 0, 0, 0);
        }

        // Scan + split hi/lo dump (two b32 per (mt,r)), swizzled
#pragma unroll
        for (int mt = 0; mt < 2; ++mt)
#pragma unroll
            for (int r = 0; r < 16; ++r) {
                float t0 = fmaf(lr, zr[r], acc[mt][0][r]); t0 = fmaf(-li, zi[r], t0);
                float t1 = fmaf(li, zr[r], acc[mt][1][r]); t1 = fmaf(lr, zi[r], t1);
                zr[r] = t0; zi[r] = t1;
                bf16x2 hv, lv;
                { __bf16 _h = (__bf16)t0; hv[0] = _h; lv[0] = (__bf16)(t0 - (float)_h); }
                { __bf16 _h = (__bf16)t1; hv[1] = _h; lv[1] = (__bf16)(t1 - (float)_h); }
                int row = mt * 32 + crow(r, lane);
                *(bf16x2*)&sX[swzX(row, w * 64 + 2 * l31)]       = hv;
                *(bf16x2*)&sX[swzX(row, 256 + w * 64 + 2 * l31)] = lv;
            }
        __syncthreads();
    }

    // Drain: out-GEMM for sub = LCH/2 - 1
    {
        f32x16 ya0, ya1, ya2;
#pragma unroll
        for (int r = 0; r < 16; ++r) { ya0[r] = 0.f; ya1[r] = 0.f; ya2[r] = 0.f; }
#pragma unroll
        for (int kk = 0; kk < 16; ++kk) {
            bf16x8 xah = ldfrag(&sX[swzX(mtile * 32 + l31, kk * 16 + kh * 8)]);
            bf16x8 xal = ldfrag(&sX[swzX(mtile * 32 + l31, 256 + kk * 16 + kh * 8)]);
            ya0 = __builtin_amdgcn_mfma_f32_32x32x16_bf16(xah, wfh[kk], ya0, 0, 0, 0);
            ya1 = __builtin_amdgcn_mfma_f32_32x32x16_bf16(xal, wfh[kk], ya1, 0, 0, 0);
            ya2 = __builtin_amdgcn_mfma_f32_32x32x16_bf16(xah, wfl[kk], ya2, 0, 0, 0);
        }
        int t = c * LCH + (LCH / 2 - 1) * 2 + mtile;
#pragma unroll
        for (int r = 0; r < 16; ++r)
            Y[((size_t)t * NBB + crow(r, lane)) * NYY + ntile * 32 + l31] =
                (ya0[r] + ya1[r]) + ya2[r] + ybias;
    }
}

// ---------------------------------------------------------------------------
extern "C" void kernel_launch(void* const* d_in, const int* in_sizes, int n_in,
                              void* d_out, int out_size, void* d_ws, size_t ws_size,
                              hipStream_t stream) {
    const float* y0    = (const float*)d_in[0];
    const float* U     = (const float*)d_in[1];
    const float* lre   = (const float*)d_in[2];
    const float* lim   = (const float*)d_in[3];
    const float* B     = (const float*)d_in[4];
    const float* W_y2x = (const float*)d_in[5];
    const float* b_y2x = (const float*)d_in[6];
    const float* W_x2y = (const float*)d_in[7];
    const float* b_x2y = (const float*)d_in[8];
    float* Y = (float*)d_out;

    char* p = (char*)d_ws;
    float2* E        = (float2*)p; p += (size_t)CCH * 4096 * sizeof(float2);   // 8.4 MB
    float2* Carry    = (float2*)p; p += (size_t)CCH * 4096 * sizeof(float2);   // 8.4 MB
    float2* Esup     = (float2*)p; p += (size_t)SEGN * 4096 * sizeof(float2);  // 256 KB
    float2* x0p      = (float2*)p; p += (size_t)4096 * sizeof(float2);         // 32 KB
    unsigned short* Bph = (unsigned short*)p; p += 16384 * sizeof(unsigned short);
    unsigned short* Bpl = (unsigned short*)p; p += 16384 * sizeof(unsigned short);
    unsigned short* Wph = (unsigned short*)p; p += 16384 * sizeof(unsigned short);
    unsigned short* Wpl = (unsigned short*)p; p += 16384 * sizeof(unsigned short);

    k_prep <<<dim3(96),  dim3(256), 0, stream>>>(B, W_x2y, y0, W_y2x, b_y2x, Bph, Bpl, Wph, Wpl, x0p);
    k_pass1<<<dim3(CCH), dim3(256), 0, stream>>>(U, Bph, Bpl, lre, lim, E);
    k_cseg <<<dim3(128), dim3(256), 0, stream>>>(lre, lim, E, Esup);
    k_cexp2<<<dim3(128), dim3(256), 0, stream>>>(lre, lim, x0p, Esup, E, Carry);
    k_pass2<<<dim3(CCH), dim3(256), 0, stream>>>(U, Bph, Bpl, Wph, Wpl, lre, lim, b_x2y, Carry, Y);
}